// Round 9
// baseline (93.942 us; speedup 1.0000x reference)
//
#include <hip/hip_runtime.h>
#include <math.h>

#define SRATE   32000
#define NFFT    1024
#define HOP     320
#define NBINS   513
#define NMELS   128
#define NFRAMES 1001
#define NB      16
#define TLEN    320000
#define PCEN_EPS 1e-6f
#define LN_EPS   1e-6f
#define MAXW     64   // max nonzero band width per mel column (measured ~27)

// ---- parallel-scan decomposition of the PCEN EMA ----
#define CL      16                    // chunk length (timesteps)
#define NCHUNK  63                    // ceil(1001/16)

// ---- four-step FFT geometry: 1024 = 32 x 32, LDS pitch 33 kills bank dup ----
#define CPF     4                     // complex FFTs per block (8 frames)
#define LPITCH  33

// bit-reverse-5 (involution)
__device__ __constant__ static const int BR5_[1] = {0}; // placeholder (unused)
constexpr int BR5[32] = {0,16,8,24,4,20,12,28,2,18,10,26,6,22,14,30,
                         1,17,9,25,5,21,13,29,3,19,11,27,7,23,15,31};

// ---------------------------------------------------------------------------
// Fully-unrolled 32-point DIF FFT, natural input, bit-reversed output:
// y[q] = X[BR5[q]]. All twiddles are compile-time literals.
__device__ __forceinline__ void fft32(float2* y) {
    constexpr float C16[16] = {
        1.f, 0.98078528f, 0.92387953f, 0.83146961f,
        0.70710678f, 0.55557023f, 0.38268343f, 0.19509032f,
        0.f, -0.19509032f, -0.38268343f, -0.55557023f,
        -0.70710678f, -0.83146961f, -0.92387953f, -0.98078528f};
    constexpr float S16[16] = {
        0.f, 0.19509032f, 0.38268343f, 0.55557023f,
        0.70710678f, 0.83146961f, 0.92387953f, 0.98078528f,
        1.f, 0.98078528f, 0.92387953f, 0.83146961f,
        0.70710678f, 0.55557023f, 0.38268343f, 0.19509032f};
    #pragma unroll
    for (int h = 16; h >= 1; h >>= 1) {
        #pragma unroll
        for (int b = 0; b < 32; b += 2 * h) {
            #pragma unroll
            for (int j = 0; j < h; ++j) {
                float2 u = y[b + j], w = y[b + j + h];
                float sr = u.x - w.x, si = u.y - w.y;
                y[b + j] = make_float2(u.x + w.x, u.y + w.y);
                const float wr = C16[j * (16 / h)];
                const float wi = -S16[j * (16 / h)];
                y[b + j + h] = make_float2(sr * wr - si * wi, sr * wi + si * wr);
            }
        }
    }
}

// ---------------------------------------------------------------------------
// Parallel prep: one block per mel packs the filterbank band; 8 extra blocks
// build winT (transposed window) and twrow (per-column four-step twiddles).
__global__ __launch_bounds__(256) void k_prep(
    const float* __restrict__ fb, int* __restrict__ kmin, int* __restrict__ klen,
    float* __restrict__ wv, float* __restrict__ winT, float2* __restrict__ twrow)
{
    const int blk = blockIdx.x;
    const int tid = threadIdx.x;
    if (blk < NMELS) {
        const int m = blk;
        __shared__ int smin[4], smax[4];
        int lmin = 1 << 30, lmax = -1;
        for (int k = tid; k < NBINS; k += 256) {
            if (fb[k * NMELS + m] > 0.f) {
                if (k < lmin) lmin = k;
                if (k > lmax) lmax = k;
            }
        }
        #pragma unroll
        for (int off = 32; off; off >>= 1) {
            int om = __shfl_xor(lmin, off); if (om < lmin) lmin = om;
            int ox = __shfl_xor(lmax, off); if (ox > lmax) lmax = ox;
        }
        if ((tid & 63) == 0) { smin[tid >> 6] = lmin; smax[tid >> 6] = lmax; }
        __syncthreads();
        int k0 = min(min(smin[0], smin[1]), min(smin[2], smin[3]));
        int k1 = max(max(smax[0], smax[1]), max(smax[2], smax[3]));
        int L  = (k1 < 0) ? 0 : min(k1 - k0 + 1, MAXW);
        if (tid == 0) { kmin[m] = (k1 < 0) ? 0 : k0; klen[m] = L; }
        if (tid < L) wv[m * MAXW + tid] = fb[(k0 + tid) * NMELS + m];
    } else {
        const int i = (blk - NMELS) * 256 + tid;   // 0..2047
        if (i < NFFT) {
            // winT[c*32 + r] = hann(c + 32 r)
            float sp = sinpif((float)i * (1.0f / (float)NFFT));
            winT[((i & 31) << 5) | (i >> 5)] = sp * sp;
        } else {
            const int e = i - NFFT;                // 0..1023
            const int c = e >> 5, k1 = e & 31;
            const int n = c * k1;                  // <= 961
            float sn, cn;
            sincospif((float)n * (1.0f / 512.0f), &sn, &cn);
            twrow[e] = make_float2(cn, -sn);       // W_1024^n
        }
    }
}

// ---------------------------------------------------------------------------
// Mel-spectrogram via four-step FFT. One block = 4 complex FFTs = 8 frames.
// Phase A (threads 0..127): 32-pt in-register DFT over r of x[c+32r] (windowed),
//   twiddle by W^{c*k1}, write Z[c][k1] to LDS (pitch 33).
// Phase B (threads 0..127): 32-pt in-register DFT over c (in place, column k1).
// Mel (all 256): on-the-fly two-for-one untangle + band dot product.
__global__ __launch_bounds__(256) void k_melspec(
    const float* __restrict__ x,
    const int*   __restrict__ kmin,
    const int*   __restrict__ klen,
    const float* __restrict__ wv,
    const float* __restrict__ fb,       // dense fallback
    const float* __restrict__ winT,
    const float2* __restrict__ twrow,
    float* __restrict__ E,
    int usePacked)
{
    __shared__ float2 Ld[CPF][LPITCH * 32];   // 33.8 KB

    const int tid = threadIdx.x;
    const int g   = blockIdx.x;               // frames 8g .. 8g+7

    // ---- phase A ----
    if (tid < 32 * CPF) {
        const int v = tid >> 5, c = tid & 31;
        const int fa = 8 * g + 2 * v, fbf = fa + 1;
        const int ba = fa / NFRAMES,  ta = fa  - ba * NFRAMES;
        const int bb = fbf / NFRAMES, tb = fbf - bb * NFRAMES;
        const float* xa = x + (size_t)ba * TLEN;
        const float* xb = x + (size_t)bb * TLEN;
        const int basea = ta * HOP - (NFFT / 2);
        const int baseb = tb * HOP - (NFFT / 2);
        float2 y[32];
        const bool safe = (basea >= 0) && (baseb >= 0) &&
                          (basea + NFFT - 1 < TLEN) && (baseb + NFFT - 1 < TLEN);
        if (usePacked && safe) {
            #pragma unroll
            for (int r = 0; r < 32; ++r) {
                const int i = c + 32 * r;
                const float w = winT[(c << 5) + r];
                y[r] = make_float2(xa[basea + i] * w, xb[baseb + i] * w);
            }
        } else {
            #pragma unroll
            for (int r = 0; r < 32; ++r) {
                const int i = c + 32 * r;
                int ja = basea + i;
                ja = (ja < 0) ? -ja : ((ja >= TLEN) ? (2 * TLEN - 2 - ja) : ja);
                int jb = baseb + i;
                jb = (jb < 0) ? -jb : ((jb >= TLEN) ? (2 * TLEN - 2 - jb) : jb);
                float w;
                if (usePacked) w = winT[(c << 5) + r];
                else { float sp = sinpif((float)i * (1.0f / (float)NFFT)); w = sp * sp; }
                y[r] = make_float2(xa[ja] * w, xb[jb] * w);
            }
        }
        fft32(y);
        // twiddle + write, natural k1 order (y[BR5[k1]] = Y[c][k1])
        const float2* trow = twrow + (c << 5);
        #pragma unroll
        for (int k1 = 0; k1 < 32; ++k1) {
            float2 val = y[BR5[k1]];
            float2 w;
            if (usePacked) w = trow[k1];
            else {
                float sn, cn;
                sincospif((float)(c * k1) * (1.0f / 512.0f), &sn, &cn);
                w = make_float2(cn, -sn);
            }
            Ld[v][LPITCH * c + k1] =
                make_float2(val.x * w.x - val.y * w.y,
                            val.x * w.y + val.y * w.x);
        }
    }
    __syncthreads();

    // ---- phase B: column FFT, in place (thread owns column k1) ----
    if (tid < 32 * CPF) {
        const int v = tid >> 5, k1 = tid & 31;
        float2 y[32];
        #pragma unroll
        for (int cc = 0; cc < 32; ++cc) y[cc] = Ld[v][LPITCH * cc + k1];
        fft32(y);
        // X[k1 + 32*k2] -> slot [33*k2 + k1]
        #pragma unroll
        for (int k2 = 0; k2 < 32; ++k2)
            Ld[v][LPITCH * k2 + k1] = y[BR5[k2]];
    }
    __syncthreads();

    // ---- mel projection with on-the-fly two-for-one untangle ----
    {
        const int m  = tid & 127;
        const int vh = tid >> 7;
        #pragma unroll
        for (int q = 0; q < 2; ++q) {
            const int vv = vh + 2 * q;
            const int f0 = 8 * g + 2 * vv;
            float acc0 = 0.f, acc1 = 0.f;
            if (usePacked) {
                const int k0 = kmin[m], L = klen[m];
                const float* w = wv + m * MAXW;
                for (int j = 0; j < L; ++j) {
                    const int k  = k0 + j;
                    const int kr = (NFFT - k) & (NFFT - 1);
                    float2 Z  = Ld[vv][LPITCH * (k  >> 5) + (k  & 31)];
                    float2 Zr = Ld[vv][LPITCH * (kr >> 5) + (kr & 31)];
                    float x1r = Z.x + Zr.x, x1i = Z.y - Zr.y;
                    float x2r = Z.y + Zr.y, x2i = Zr.x - Z.x;
                    float ww = w[j];
                    acc0 += (x1r * x1r + x1i * x1i) * ww;
                    acc1 += (x2r * x2r + x2i * x2i) * ww;
                }
            } else {
                for (int k = 0; k < NBINS; ++k) {
                    const int kr = (NFFT - k) & (NFFT - 1);
                    float2 Z  = Ld[vv][LPITCH * (k  >> 5) + (k  & 31)];
                    float2 Zr = Ld[vv][LPITCH * (kr >> 5) + (kr & 31)];
                    float x1r = Z.x + Zr.x, x1i = Z.y - Zr.y;
                    float x2r = Z.y + Zr.y, x2i = Zr.x - Z.x;
                    float ww = fb[k * NMELS + m];
                    acc0 += (x1r * x1r + x1i * x1i) * ww;
                    acc1 += (x2r * x2r + x2i * x2i) * ww;
                }
            }
            E[(size_t)f0 * NMELS + m]       = 0.25f * acc0;
            E[(size_t)(f0 + 1) * NMELS + m] = 0.25f * acc1;
        }
    }
}

// ---------------------------------------------------------------------------
// PCEN phase 1 (R6 form): per-(b,chunk,m) affine offset with 16 loads in
// flight; merges 4 FMA chains via a^4/a^8/a^12. Snapshots E[:,0,:].
__global__ __launch_bounds__(256) void k_pcen_chunk(
    const float* __restrict__ E, float* __restrict__ Bws,
    float* __restrict__ E0ws, const float* __restrict__ p_ls)
{
    const int gid = blockIdx.x * blockDim.x + threadIdx.x;
    const int m = gid & (NMELS - 1);
    const int c = (gid >> 7) % NCHUNK;
    const int b = gid / (NMELS * NCHUNK);

    const float s = expf(p_ls[0]);
    const float a = 1.f - s;

    const int t0 = c * CL;
    const int L  = (t0 + CL <= NFRAMES) ? CL : (NFRAMES - t0);
    const float* col = E + (size_t)b * NFRAMES * NMELS + m;

    if (c == 0) E0ws[b * NMELS + m] = col[0];

    float Bacc;
    if (L == CL) {
        float e[CL];
        #pragma unroll
        for (int j = 0; j < CL; ++j)
            e[j] = col[(size_t)(t0 + j) * NMELS];
        float p0 = 0.f, p1 = 0.f, p2 = 0.f, p3 = 0.f;
        #pragma unroll
        for (int u = 0; u < 4; ++u) {
            p0 = a * p0 + s * e[u];
            p1 = a * p1 + s * e[4 + u];
            p2 = a * p2 + s * e[8 + u];
            p3 = a * p3 + s * e[12 + u];
        }
        const float a2 = a * a, a4 = a2 * a2, a8 = a4 * a4, a12 = a8 * a4;
        Bacc = a12 * p0 + a8 * p1 + a4 * p2 + p3;
    } else {
        Bacc = 0.f;
        for (int j = 0; j < L; ++j)
            Bacc = a * Bacc + s * col[(size_t)(t0 + j) * NMELS];
    }
    Bws[gid] = Bacc;
}

// ---------------------------------------------------------------------------
// PCEN phase 2 + LN (R6 form): one block = (b, chunk-pair); each half
// self-scans Bws with 8-wide batched loads, replays its chunk with PCEN into
// LDS, then 4 waves layernorm the 32 frames in place.
__global__ __launch_bounds__(256) void k_pcen_ln(
    float* __restrict__ E, const float* __restrict__ Bws,
    const float* __restrict__ E0ws,
    const float* __restrict__ p_ls, const float* __restrict__ p_la,
    const float* __restrict__ p_ld, const float* __restrict__ p_lr)
{
    __shared__ float sm[2 * CL][NMELS];   // 16 KB

    const int tid  = threadIdx.x;
    const int half = tid >> 7;
    const int m    = tid & 127;
    const int b    = blockIdx.x >> 5;     // 32 chunk-pairs per batch
    const int cp   = blockIdx.x & 31;
    const int c    = cp * 2 + half;

    const float s     = expf(p_ls[0]);
    const float alpha = expf(p_la[0]);
    const float delta = expf(p_ld[0]);
    const float r     = expf(p_lr[0]);
    const float dr    = __powf(delta, r);
    const float a     = 1.f - s;
    const float a2 = a * a, a4 = a2 * a2, a8 = a4 * a4;
    const float a16 = a8 * a8;            // a^CL (all scanned chunks full)

    if (c < NCHUNK) {
        float M = E0ws[b * NMELS + m];
        const float* Bcol = Bws + (size_t)b * NCHUNK * NMELS + m;
        int cc = 0;
        for (; cc + 8 <= c; cc += 8) {
            float b0 = Bcol[(size_t)(cc + 0) * NMELS];
            float b1 = Bcol[(size_t)(cc + 1) * NMELS];
            float b2 = Bcol[(size_t)(cc + 2) * NMELS];
            float b3 = Bcol[(size_t)(cc + 3) * NMELS];
            float b4 = Bcol[(size_t)(cc + 4) * NMELS];
            float b5 = Bcol[(size_t)(cc + 5) * NMELS];
            float b6 = Bcol[(size_t)(cc + 6) * NMELS];
            float b7 = Bcol[(size_t)(cc + 7) * NMELS];
            M = a16 * M + b0; M = a16 * M + b1; M = a16 * M + b2; M = a16 * M + b3;
            M = a16 * M + b4; M = a16 * M + b5; M = a16 * M + b6; M = a16 * M + b7;
        }
        for (; cc < c; ++cc)
            M = a16 * M + Bcol[(size_t)cc * NMELS];

        const int t0 = c * CL;
        const int L  = (t0 + CL <= NFRAMES) ? CL : (NFRAMES - t0);
        const float* col = E + ((size_t)b * NFRAMES + t0) * NMELS + m;
        for (int j = 0; j < L; ++j) {
            float e = col[(size_t)j * NMELS];
            M = a * M + s * e;
            float den = __powf(PCEN_EPS + M, alpha);
            sm[half * CL + j][m] = __powf(e / den + delta, r) - dr;
        }
    }
    __syncthreads();

    const int wid  = tid >> 6;
    const int lane = tid & 63;
    for (int row = wid; row < 2 * CL; row += 4) {
        const int cc = cp * 2 + (row >> 4);
        if (cc >= NCHUNK) continue;
        const int j   = row & (CL - 1);
        const int tt0 = cc * CL;
        const int LL  = (tt0 + CL <= NFRAMES) ? CL : (NFRAMES - tt0);
        if (j >= LL) continue;
        float v0 = sm[row][lane], v1 = sm[row][lane + 64];
        float sum = v0 + v1;
        float sq  = v0 * v0 + v1 * v1;
        #pragma unroll
        for (int off = 32; off; off >>= 1) {
            sum += __shfl_xor(sum, off);
            sq  += __shfl_xor(sq,  off);
        }
        float mu  = sum * (1.f / 128.f);
        float var = sq * (1.f / 128.f) - mu * mu;
        float inv = rsqrtf(var + LN_EPS);
        float* p = E + ((size_t)b * NFRAMES + tt0 + j) * NMELS;
        p[lane]      = (v0 - mu) * inv;
        p[lane + 64] = (v1 - mu) * inv;
    }
}

// ---------------------------------------------------------------------------
// Fallback serial PCEN + LN (used only if workspace is too small).
__global__ __launch_bounds__(256) void k_pcen_serial(
    float* __restrict__ E,
    const float* __restrict__ p_ls, const float* __restrict__ p_la,
    const float* __restrict__ p_ld, const float* __restrict__ p_lr)
{
    const int gid = blockIdx.x * blockDim.x + threadIdx.x;
    const int b = gid >> 7;
    const int m = gid & 127;

    const float s     = expf(p_ls[0]);
    const float alpha = expf(p_la[0]);
    const float delta = expf(p_ld[0]);
    const float r     = expf(p_lr[0]);
    const float dr    = powf(delta, r);
    const float a     = 1.f - s;

    float* col = E + (size_t)b * NFRAMES * NMELS + m;
    float M = col[0];
    for (int t = 0; t < NFRAMES; ++t) {
        float e = col[(size_t)t * NMELS];
        M = a * M + s * e;
        float den = __powf(PCEN_EPS + M, alpha);
        float p   = __powf(e / den + delta, r) - dr;
        col[(size_t)t * NMELS] = p;
    }
}

__global__ __launch_bounds__(256) void k_ln(float* __restrict__ out) {
    const int wid  = threadIdx.x >> 6;
    const int lane = threadIdx.x & 63;
    const int row  = blockIdx.x * 4 + wid;
    float* p = out + (size_t)row * NMELS;
    float v0 = p[lane], v1 = p[lane + 64];
    float sum = v0 + v1;
    float sq  = v0 * v0 + v1 * v1;
    #pragma unroll
    for (int off = 32; off; off >>= 1) {
        sum += __shfl_xor(sum, off);
        sq  += __shfl_xor(sq,  off);
    }
    float mu  = sum * (1.f / 128.f);
    float var = sq * (1.f / 128.f) - mu * mu;
    float inv = rsqrtf(var + LN_EPS);
    p[lane]      = (v0 - mu) * inv;
    p[lane + 64] = (v1 - mu) * inv;
}

// ---------------------------------------------------------------------------
extern "C" void kernel_launch(void* const* d_in, const int* in_sizes, int n_in,
                              void* d_out, int out_size, void* d_ws, size_t ws_size,
                              hipStream_t stream) {
    const float* x   = (const float*)d_in[0];
    const float* fb  = (const float*)d_in[1];
    const float* lsp = (const float*)d_in[2];
    const float* lap = (const float*)d_in[3];
    const float* ldp = (const float*)d_in[4];
    const float* lrp = (const float*)d_in[5];
    float* out = (float*)d_out;

    // ws layout (floats): kmin[128] klen[128] wv[8192] winT[1024]
    //                     twrow[2048] Bws[129024] E0ws[2048]
    const size_t packElems = 128 + 128 + 8192 + 1024 + 2048;
    const size_t scanElems = (size_t)NB * NCHUNK * NMELS;   // 129024
    const size_t needPack  = packElems * 4;
    const size_t needScan  = (packElems + scanElems + (size_t)NB * NMELS) * 4;

    int usePacked = (ws_size >= needPack) ? 1 : 0;
    int useScan   = (ws_size >= needScan) ? 1 : 0;

    int*    kmin  = (int*)d_ws;
    int*    klen  = kmin + NMELS;
    float*  wv    = (float*)(klen + NMELS);
    float*  winT  = wv + (size_t)NMELS * MAXW;
    float2* twrow = (float2*)(winT + NFFT);
    float*  Bws   = (float*)(twrow + 1024);
    float*  E0ws  = Bws + scanElems;

    if (usePacked)
        k_prep<<<NMELS + 8, 256, 0, stream>>>(fb, kmin, klen, wv, winT, twrow);

    k_melspec<<<NB * NFRAMES / 8, 256, 0, stream>>>(
        x, kmin, klen, wv, fb, winT, twrow, out, usePacked);

    if (useScan) {
        const int nThread = NB * NCHUNK * NMELS;                 // 129024
        k_pcen_chunk<<<nThread / 256, 256, 0, stream>>>(out, Bws, E0ws, lsp);
        k_pcen_ln<<<NB * 32, 256, 0, stream>>>(out, Bws, E0ws, lsp, lap, ldp, lrp);
    } else {
        k_pcen_serial<<<(NB * NMELS) / 256, 256, 0, stream>>>(out, lsp, lap, ldp, lrp);
        k_ln<<<(NB * NFRAMES) / 4, 256, 0, stream>>>(out);
    }
}